// Round 1
// baseline (231.041 us; speedup 1.0000x reference)
//
#include <hip/hip_runtime.h>
#include <hip/hip_bf16.h>

// MoE: B=2,S=2048,D=512,E=8,H=1024,TOP_K=2. fp32 in/out, bf16 MFMA internally.
// Pipeline: memsets -> cvt(fp32->bf16) -> router(fp32) -> GEMM1(routed, silu->Hbuf)
//           -> GEMM2(routed, atomic weighted add -> out) -> gate/up (silu*up -> ACT)
//           -> down (RMW add -> out).

#define NTOK 4096
#define DDIM 512
#define HDIM 1024
#define NEXP 8
#define CAP  4096

typedef unsigned short u16;
typedef __attribute__((ext_vector_type(8))) short short8;
typedef __attribute__((ext_vector_type(4))) float f32x4;

__device__ __forceinline__ u16 f2bf(float f) {
  unsigned u = __float_as_uint(f);
  u += 0x7fffu + ((u >> 16) & 1u);   // RNE
  return (u16)(u >> 16);
}

__device__ __forceinline__ float silu_f(float v) { return v / (1.0f + __expf(-v)); }

__device__ __forceinline__ void gload16(const u16* g, u16* l) {
  __builtin_amdgcn_global_load_lds((const __attribute__((address_space(1))) void*)g,
                                   (__attribute__((address_space(3))) void*)l, 16, 0, 0);
}

// ---------------- fp32 -> bf16 conversion for all MFMA operands ----------------
__global__ __launch_bounds__(256) void cvt_all(
    const float* __restrict__ x,  const float* __restrict__ w1,
    const float* __restrict__ w2, const float* __restrict__ sgg,
    const float* __restrict__ sgu, const float* __restrict__ sgd,
    u16* __restrict__ xb, u16* __restrict__ w1b, u16* __restrict__ w2b,
    u16* __restrict__ sggb, u16* __restrict__ sgub, u16* __restrict__ sgdb) {
  const float* src; u16* dst; int n4;
  switch (blockIdx.y) {
    case 0:  src = x;   dst = xb;   n4 = NTOK * DDIM / 4;        break;
    case 1:  src = w1;  dst = w1b;  n4 = NEXP * HDIM * DDIM / 4; break;
    case 2:  src = w2;  dst = w2b;  n4 = NEXP * HDIM * DDIM / 4; break;
    case 3:  src = sgg; dst = sggb; n4 = HDIM * DDIM / 4;        break;
    case 4:  src = sgu; dst = sgub; n4 = HDIM * DDIM / 4;        break;
    default: src = sgd; dst = sgdb; n4 = HDIM * DDIM / 4;        break;
  }
  int i = blockIdx.x * blockDim.x + threadIdx.x;
  const int stride = gridDim.x * blockDim.x;
  for (; i < n4; i += stride) {
    float4 v = ((const float4*)src)[i];
    ushort4 o;
    o.x = f2bf(v.x); o.y = f2bf(v.y); o.z = f2bf(v.z); o.w = f2bf(v.w);
    ((ushort4*)dst)[i] = o;
  }
}

// ---------------- router: fp32 logits, top-2, softmax, list build ----------------
__global__ __launch_bounds__(256) void router_kernel(
    const float* __restrict__ x, const float* __restrict__ gw,
    int* __restrict__ counts, int* __restrict__ elist, float* __restrict__ wlist) {
  const int lane = threadIdx.x & 63;
  const int wid  = threadIdx.x >> 6;
  const int t = blockIdx.x * 4 + wid;           // one wave per token
  const float4* xr = (const float4*)(x + (size_t)t * DDIM + lane * 8);
  const float4 x0 = xr[0], x1 = xr[1];
  float p[NEXP];
#pragma unroll
  for (int e = 0; e < NEXP; ++e) {
    const float4* gr = (const float4*)(gw + (size_t)e * DDIM + lane * 8);
    const float4 g0 = gr[0], g1 = gr[1];
    p[e] = x0.x*g0.x + x0.y*g0.y + x0.z*g0.z + x0.w*g0.w +
           x1.x*g1.x + x1.y*g1.y + x1.z*g1.z + x1.w*g1.w;
  }
#pragma unroll
  for (int e = 0; e < NEXP; ++e) {
#pragma unroll
    for (int m = 32; m >= 1; m >>= 1) p[e] += __shfl_xor(p[e], m);
  }
  if (lane == 0) {
    int i0 = 0; float v0 = p[0];
#pragma unroll
    for (int e = 1; e < NEXP; ++e) if (p[e] > v0) { v0 = p[e]; i0 = e; }
    int i1 = -1; float v1 = -3.0e38f;
#pragma unroll
    for (int e = 0; e < NEXP; ++e) if (e != i0 && p[e] > v1) { v1 = p[e]; i1 = e; }
    const float ex1 = __expf(v1 - v0);          // v0 >= v1
    const float inv = 1.0f / (1.0f + ex1);
    const int pos0 = atomicAdd(&counts[i0], 1);
    elist[i0 * CAP + pos0] = t * 2;
    wlist[i0 * CAP + pos0] = inv;
    const int pos1 = atomicAdd(&counts[i1], 1);
    elist[i1 * CAP + pos1] = t * 2 + 1;
    wlist[i1 * CAP + pos1] = ex1 * inv;
  }
}

// ---------------- TN GEMM template, 128x128 tile, BK=32, 4 waves ----------------
// MODE 0: routed up   — gather Xb rows (entry>>1), silu -> Hbuf[entry]
// MODE 1: routed down — gather Hbuf rows (entry), atomicAdd(w * acc) -> out[entry>>1]
// MODE 2: shared g/up — A=Xb, two B; silu(c0)*c1 -> ACT
// MODE 3: shared down — A=ACT; out += acc
template <int MODE, int KDIM, int NFULL>
__global__ __launch_bounds__(256) void gemm_tn(
    const u16* __restrict__ A, const u16* __restrict__ B0, const u16* __restrict__ B1,
    u16* __restrict__ obf, float* __restrict__ ofp,
    const int* __restrict__ counts, const int* __restrict__ elist,
    const float* __restrict__ wlist) {
  constexpr int NUMB  = (MODE == 2) ? 2 : 1;
  constexpr int KSTEP = KDIM / 32;
  constexpr int LDC   = (MODE == 0 || MODE == 2) ? HDIM : DDIM;
  const int n0 = blockIdx.x * 128;
  const int m0 = blockIdx.y * 128;

  int mlim;
  const u16* Bp0 = B0;
  const int* lst = nullptr; const float* wl = nullptr;
  if constexpr (MODE == 0 || MODE == 1) {
    const int e = blockIdx.z;
    mlim = counts[e];
    lst = elist + e * CAP;
    wl  = wlist + e * CAP;
    Bp0 = B0 + (size_t)e * NFULL * KDIM;
  } else {
    mlim = NTOK;
  }
  if (m0 >= mlim) return;

  __shared__ __align__(16) u16 As[128 * 32];
  __shared__ __align__(16) u16 Bs[NUMB][128 * 32];
  __shared__ int   rowE[128];
  __shared__ float rowW[128];

  const int tid  = threadIdx.x;
  const int wid  = tid >> 6, lane = tid & 63;

  if constexpr (MODE == 0 || MODE == 1) {
    if (tid < 128) {
      int idx = m0 + tid; if (idx > mlim - 1) idx = mlim - 1;  // clamp padding rows
      rowE[tid] = lst[idx];
      rowW[tid] = wl[idx];
    }
    __syncthreads();
  }

  // staging: 2 x 16B per thread per operand per K-step; LDS dest linear per wave
  const u16* aG[2]; const u16* bG0[2]; const u16* bG1[2];
  u16* aL[2]; u16* bL0[2]; u16* bL1[2];
#pragma unroll
  for (int p = 0; p < 2; ++p) {
    const int slot = (wid + p * 4) * 64 + lane;   // 0..511
    const int r = slot >> 2, kc = slot & 3;
    aL[p]  = As + slot * 8;
    bL0[p] = &Bs[0][slot * 8];
    int arow;
    if constexpr (MODE == 0)      arow = rowE[r] >> 1;
    else if constexpr (MODE == 1) arow = rowE[r];
    else                          arow = m0 + r;
    aG[p]  = A   + (size_t)arow * KDIM + kc * 8;
    bG0[p] = Bp0 + (size_t)(n0 + r) * KDIM + kc * 8;
    if constexpr (NUMB == 2) {
      bL1[p] = &Bs[1][slot * 8];
      bG1[p] = B1 + (size_t)(n0 + r) * KDIM + kc * 8;
    }
  }

  const int wm = (wid >> 1) * 64, wn = (wid & 1) * 64;
  const int lr = lane & 15, lk = lane >> 4;

  const f32x4 zero = {0.f, 0.f, 0.f, 0.f};
  f32x4 acc0[4][4], acc1[4][4];
#pragma unroll
  for (int i = 0; i < 4; ++i)
#pragma unroll
    for (int j = 0; j < 4; ++j) { acc0[i][j] = zero; acc1[i][j] = zero; }

  for (int kt = 0; kt < KSTEP; ++kt) {
#pragma unroll
    for (int p = 0; p < 2; ++p) {
      gload16(aG[p]  + kt * 32, aL[p]);
      gload16(bG0[p] + kt * 32, bL0[p]);
      if constexpr (NUMB == 2) gload16(bG1[p] + kt * 32, bL1[p]);
    }
    __syncthreads();   // drains vmcnt (incl. global_load_lds) before reads

    short8 a[4], b0[4], b1[4];
#pragma unroll
    for (int i = 0; i < 4; ++i)
      a[i] = *(const short8*)&As[(wm + i * 16 + lr) * 32 + lk * 8];
#pragma unroll
    for (int j = 0; j < 4; ++j)
      b0[j] = *(const short8*)&Bs[0][(wn + j * 16 + lr) * 32 + lk * 8];
    if constexpr (NUMB == 2) {
#pragma unroll
      for (int j = 0; j < 4; ++j)
        b1[j] = *(const short8*)&Bs[1][(wn + j * 16 + lr) * 32 + lk * 8];
    }
#pragma unroll
    for (int i = 0; i < 4; ++i)
#pragma unroll
      for (int j = 0; j < 4; ++j) {
        acc0[i][j] = __builtin_amdgcn_mfma_f32_16x16x32_bf16(a[i], b0[j], acc0[i][j], 0, 0, 0);
        if constexpr (NUMB == 2)
          acc1[i][j] = __builtin_amdgcn_mfma_f32_16x16x32_bf16(a[i], b1[j], acc1[i][j], 0, 0, 0);
      }
    __syncthreads();   // LDS reuse next iteration
  }

  // epilogue: C/D layout col=lane&15, row=(lane>>4)*4+r  [m89-verified]
#pragma unroll
  for (int i = 0; i < 4; ++i) {
#pragma unroll
    for (int j = 0; j < 4; ++j) {
      const int col = n0 + wn + j * 16 + lr;
#pragma unroll
      for (int r = 0; r < 4; ++r) {
        const int m = wm + i * 16 + lk * 4 + r;
        if constexpr (MODE == 0) {
          if (m0 + m < mlim) {
            const int hrow = rowE[m];
            obf[(size_t)hrow * LDC + col] = f2bf(silu_f(acc0[i][j][r]));
          }
        } else if constexpr (MODE == 1) {
          if (m0 + m < mlim) {
            const int t = rowE[m] >> 1;
            atomicAdd(&ofp[(size_t)t * LDC + col], rowW[m] * acc0[i][j][r]);
          }
        } else if constexpr (MODE == 2) {
          const float v = silu_f(acc0[i][j][r]) * acc1[i][j][r];
          obf[(size_t)(m0 + m) * LDC + col] = f2bf(v);
        } else {
          ofp[(size_t)(m0 + m) * LDC + col] += acc0[i][j][r];
        }
      }
    }
  }
}

extern "C" void kernel_launch(void* const* d_in, const int* in_sizes, int n_in,
                              void* d_out, int out_size, void* d_ws, size_t ws_size,
                              hipStream_t stream) {
  const float* x    = (const float*)d_in[0];
  const float* gw   = (const float*)d_in[1];
  const float* w1   = (const float*)d_in[2];
  const float* w2   = (const float*)d_in[3];
  const float* sgg  = (const float*)d_in[4];
  const float* sgu  = (const float*)d_in[5];
  const float* sgd  = (const float*)d_in[6];
  float* out = (float*)d_out;

  char* ws = (char*)d_ws;
  size_t off = 0;
  auto take = [&](size_t bytes) {
    size_t r = off; off += (bytes + 255) & ~(size_t)255; return r;
  };
  int*   counts = (int*)  (ws + take(NEXP * sizeof(int)));
  int*   elist  = (int*)  (ws + take((size_t)NEXP * CAP * sizeof(int)));
  float* wlist  = (float*)(ws + take((size_t)NEXP * CAP * sizeof(float)));
  u16*   Xb     = (u16*)  (ws + take((size_t)NTOK * DDIM * 2));
  u16*   W1b    = (u16*)  (ws + take((size_t)NEXP * HDIM * DDIM * 2));
  u16*   W2b    = (u16*)  (ws + take((size_t)NEXP * DDIM * HDIM * 2));
  u16*   SGGb   = (u16*)  (ws + take((size_t)HDIM * DDIM * 2));
  u16*   SGUb   = (u16*)  (ws + take((size_t)HDIM * DDIM * 2));
  u16*   SGDb   = (u16*)  (ws + take((size_t)DDIM * HDIM * 2));
  u16*   Hbuf   = (u16*)  (ws + take((size_t)NTOK * 2 * HDIM * 2));
  u16*   ACT    = (u16*)  (ws + take((size_t)NTOK * HDIM * 2));
  if (off > ws_size) return;  // fail loudly (out stays zero)

  hipMemsetAsync(counts, 0, 256, stream);
  hipMemsetAsync(out, 0, (size_t)out_size * sizeof(float), stream);

  cvt_all<<<dim3(512, 6), 256, 0, stream>>>(x, w1, w2, sgg, sgu, sgd,
                                            Xb, W1b, W2b, SGGb, SGUb, SGDb);
  router_kernel<<<NTOK / 4, 256, 0, stream>>>(x, gw, counts, elist, wlist);

  // routed up: M<=n_e, N=1024, K=512
  gemm_tn<0, DDIM, HDIM><<<dim3(HDIM / 128, 32, NEXP), 256, 0, stream>>>(
      Xb, W1b, nullptr, Hbuf, nullptr, counts, elist, wlist);
  // routed down: M<=n_e, N=512, K=1024, atomic weighted add into out
  gemm_tn<1, HDIM, DDIM><<<dim3(DDIM / 128, 32, NEXP), 256, 0, stream>>>(
      Hbuf, W2b, nullptr, nullptr, out, counts, elist, wlist);
  // shared gate/up: M=4096, N=1024, K=512
  gemm_tn<2, DDIM, HDIM><<<dim3(HDIM / 128, NTOK / 128, 1), 256, 0, stream>>>(
      Xb, SGGb, SGUb, ACT, nullptr, nullptr, nullptr, nullptr);
  // shared down: M=4096, N=512, K=1024, out += (runs after routed atomics)
  gemm_tn<3, HDIM, DDIM><<<dim3(DDIM / 128, NTOK / 128, 1), 256, 0, stream>>>(
      ACT, SGDb, nullptr, nullptr, out, nullptr, nullptr, nullptr);
}

// Round 2
// 147.915 us; speedup vs baseline: 1.5620x; 1.5620x over previous
//
#include <hip/hip_runtime.h>
#include <hip/hip_bf16.h>

// MoE: B=2,S=2048,D=512,E=8,H=1024,TOP_K=2. fp32 in/out, bf16 MFMA internally.
// Pipeline: memset(out) -> cvt(fp32->bf16) -> router_topk (no atomics)
//           -> build_lists (ballot + LDS counter, 8 blocks)
//           -> GEMM1(routed, silu->Hbuf) -> GEMM2(routed, atomic weighted add -> out)
//           -> gate/up (silu*up -> ACT) -> down (RMW add -> out).

#define NTOK 4096
#define DDIM 512
#define HDIM 1024
#define NEXP 8
#define CAP  4096

typedef unsigned short u16;
typedef __attribute__((ext_vector_type(8))) short short8;
typedef __attribute__((ext_vector_type(4))) float f32x4;

__device__ __forceinline__ u16 f2bf(float f) {
  unsigned u = __float_as_uint(f);
  u += 0x7fffu + ((u >> 16) & 1u);   // RNE
  return (u16)(u >> 16);
}

__device__ __forceinline__ float silu_f(float v) { return v / (1.0f + __expf(-v)); }

__device__ __forceinline__ void gload16(const u16* g, u16* l) {
  __builtin_amdgcn_global_load_lds((const __attribute__((address_space(1))) void*)g,
                                   (__attribute__((address_space(3))) void*)l, 16, 0, 0);
}

// ---------------- fp32 -> bf16 conversion for all MFMA operands ----------------
__global__ __launch_bounds__(256) void cvt_all(
    const float* __restrict__ x,  const float* __restrict__ w1,
    const float* __restrict__ w2, const float* __restrict__ sgg,
    const float* __restrict__ sgu, const float* __restrict__ sgd,
    u16* __restrict__ xb, u16* __restrict__ w1b, u16* __restrict__ w2b,
    u16* __restrict__ sggb, u16* __restrict__ sgub, u16* __restrict__ sgdb) {
  const float* src; u16* dst; int n4;
  switch (blockIdx.y) {
    case 0:  src = x;   dst = xb;   n4 = NTOK * DDIM / 4;        break;
    case 1:  src = w1;  dst = w1b;  n4 = NEXP * HDIM * DDIM / 4; break;
    case 2:  src = w2;  dst = w2b;  n4 = NEXP * HDIM * DDIM / 4; break;
    case 3:  src = sgg; dst = sggb; n4 = HDIM * DDIM / 4;        break;
    case 4:  src = sgu; dst = sgub; n4 = HDIM * DDIM / 4;        break;
    default: src = sgd; dst = sgdb; n4 = HDIM * DDIM / 4;        break;
  }
  int i = blockIdx.x * blockDim.x + threadIdx.x;
  const int stride = gridDim.x * blockDim.x;
  for (; i < n4; i += stride) {
    float4 v = ((const float4*)src)[i];
    ushort4 o;
    o.x = f2bf(v.x); o.y = f2bf(v.y); o.z = f2bf(v.z); o.w = f2bf(v.w);
    ((ushort4*)dst)[i] = o;
  }
}

// ---------------- router phase 1: fp32 logits, top-2, softmax (no atomics) ------
__global__ __launch_bounds__(256) void router_topk(
    const float* __restrict__ x, const float* __restrict__ gw,
    int* __restrict__ tIdx, float2* __restrict__ tW) {
  const int lane = threadIdx.x & 63;
  const int wid  = threadIdx.x >> 6;
  const int t = blockIdx.x * 4 + wid;           // one wave per token
  const float4* xr = (const float4*)(x + (size_t)t * DDIM + lane * 8);
  const float4 x0 = xr[0], x1 = xr[1];
  float p[NEXP];
#pragma unroll
  for (int e = 0; e < NEXP; ++e) {
    const float4* gr = (const float4*)(gw + (size_t)e * DDIM + lane * 8);
    const float4 g0 = gr[0], g1 = gr[1];
    p[e] = x0.x*g0.x + x0.y*g0.y + x0.z*g0.z + x0.w*g0.w +
           x1.x*g1.x + x1.y*g1.y + x1.z*g1.z + x1.w*g1.w;
  }
#pragma unroll
  for (int e = 0; e < NEXP; ++e) {
#pragma unroll
    for (int m = 32; m >= 1; m >>= 1) p[e] += __shfl_xor(p[e], m);
  }
  if (lane == 0) {
    int i0 = 0; float v0 = p[0];
#pragma unroll
    for (int e = 1; e < NEXP; ++e) if (p[e] > v0) { v0 = p[e]; i0 = e; }
    int i1 = -1; float v1 = -3.0e38f;
#pragma unroll
    for (int e = 0; e < NEXP; ++e) if (e != i0 && p[e] > v1) { v1 = p[e]; i1 = e; }
    const float ex1 = __expf(v1 - v0);          // v0 >= v1
    const float inv = 1.0f / (1.0f + ex1);
    tIdx[t] = i0 | (i1 << 4);
    tW[t] = make_float2(inv, ex1 * inv);
  }
}

// ---------------- router phase 2: per-expert list build (ballot + LDS counter) --
__global__ __launch_bounds__(256) void build_lists(
    const int* __restrict__ tIdx, const float2* __restrict__ tW,
    int* __restrict__ counts, int* __restrict__ elist, float* __restrict__ wlist) {
  const int e = blockIdx.x;
  __shared__ int cnt;
  if (threadIdx.x == 0) cnt = 0;
  __syncthreads();
  const int lane = threadIdx.x & 63;
  int* el = elist + e * CAP;
  float* wlp = wlist + e * CAP;
  for (int base = 0; base < NTOK; base += 256) {
    const int t = base + threadIdx.x;
    const int pk = tIdx[t];
    const float2 w = tW[t];
#pragma unroll
    for (int slot = 0; slot < 2; ++slot) {
      const bool m = (((pk >> (slot * 4)) & 15) == e);
      const unsigned long long b = __ballot(m);
      const int my  = __popcll(b & ((1ull << lane) - 1));
      const int tot = __popcll(b);
      int wbase = 0;
      if (lane == 0 && tot) wbase = atomicAdd(&cnt, tot);
      wbase = __shfl(wbase, 0);
      if (m) {
        const int pos = wbase + my;
        el[pos]  = t * 2 + slot;
        wlp[pos] = slot ? w.y : w.x;
      }
    }
  }
  __syncthreads();
  if (threadIdx.x == 0) counts[e] = cnt;
}

// ---------------- TN GEMM template, 128x128 tile, BK=32, 4 waves ----------------
// MODE 0: routed up   — gather Xb rows (entry>>1), silu -> Hbuf[entry]
// MODE 1: routed down — gather Hbuf rows (entry), atomicAdd(w * acc) -> out[entry>>1]
// MODE 2: shared g/up — A=Xb, two B; silu(c0)*c1 -> ACT
// MODE 3: shared down — A=ACT; out += acc
template <int MODE, int KDIM, int NFULL>
__global__ __launch_bounds__(256) void gemm_tn(
    const u16* __restrict__ A, const u16* __restrict__ B0, const u16* __restrict__ B1,
    u16* __restrict__ obf, float* __restrict__ ofp,
    const int* __restrict__ counts, const int* __restrict__ elist,
    const float* __restrict__ wlist) {
  constexpr int NUMB  = (MODE == 2) ? 2 : 1;
  constexpr int KSTEP = KDIM / 32;
  constexpr int LDC   = (MODE == 0 || MODE == 2) ? HDIM : DDIM;
  const int n0 = blockIdx.x * 128;
  const int m0 = blockIdx.y * 128;

  int mlim;
  const u16* Bp0 = B0;
  const int* lst = nullptr; const float* wl = nullptr;
  if constexpr (MODE == 0 || MODE == 1) {
    const int e = blockIdx.z;
    mlim = counts[e];
    lst = elist + e * CAP;
    wl  = wlist + e * CAP;
    Bp0 = B0 + (size_t)e * NFULL * KDIM;
  } else {
    mlim = NTOK;
  }
  if (m0 >= mlim) return;

  __shared__ __align__(16) u16 As[128 * 32];
  __shared__ __align__(16) u16 Bs[NUMB][128 * 32];
  __shared__ int   rowE[128];
  __shared__ float rowW[128];

  const int tid  = threadIdx.x;
  const int wid  = tid >> 6, lane = tid & 63;

  if constexpr (MODE == 0 || MODE == 1) {
    if (tid < 128) {
      int idx = m0 + tid; if (idx > mlim - 1) idx = mlim - 1;  // clamp padding rows
      rowE[tid] = lst[idx];
      rowW[tid] = wl[idx];
    }
    __syncthreads();
  }

  // staging: 2 x 16B per thread per operand per K-step; LDS dest linear per wave
  const u16* aG[2]; const u16* bG0[2]; const u16* bG1[2];
  u16* aL[2]; u16* bL0[2]; u16* bL1[2];
#pragma unroll
  for (int p = 0; p < 2; ++p) {
    const int slot = (wid + p * 4) * 64 + lane;   // 0..511
    const int r = slot >> 2, kc = slot & 3;
    aL[p]  = As + slot * 8;
    bL0[p] = &Bs[0][slot * 8];
    int arow;
    if constexpr (MODE == 0)      arow = rowE[r] >> 1;
    else if constexpr (MODE == 1) arow = rowE[r];
    else                          arow = m0 + r;
    aG[p]  = A   + (size_t)arow * KDIM + kc * 8;
    bG0[p] = Bp0 + (size_t)(n0 + r) * KDIM + kc * 8;
    if constexpr (NUMB == 2) {
      bL1[p] = &Bs[1][slot * 8];
      bG1[p] = B1 + (size_t)(n0 + r) * KDIM + kc * 8;
    }
  }

  const int wm = (wid >> 1) * 64, wn = (wid & 1) * 64;
  const int lr = lane & 15, lk = lane >> 4;

  const f32x4 zero = {0.f, 0.f, 0.f, 0.f};
  f32x4 acc0[4][4], acc1[4][4];
#pragma unroll
  for (int i = 0; i < 4; ++i)
#pragma unroll
    for (int j = 0; j < 4; ++j) { acc0[i][j] = zero; acc1[i][j] = zero; }

  for (int kt = 0; kt < KSTEP; ++kt) {
#pragma unroll
    for (int p = 0; p < 2; ++p) {
      gload16(aG[p]  + kt * 32, aL[p]);
      gload16(bG0[p] + kt * 32, bL0[p]);
      if constexpr (NUMB == 2) gload16(bG1[p] + kt * 32, bL1[p]);
    }
    __syncthreads();   // drains vmcnt (incl. global_load_lds) before reads

    short8 a[4], b0[4], b1[4];
#pragma unroll
    for (int i = 0; i < 4; ++i)
      a[i] = *(const short8*)&As[(wm + i * 16 + lr) * 32 + lk * 8];
#pragma unroll
    for (int j = 0; j < 4; ++j)
      b0[j] = *(const short8*)&Bs[0][(wn + j * 16 + lr) * 32 + lk * 8];
    if constexpr (NUMB == 2) {
#pragma unroll
      for (int j = 0; j < 4; ++j)
        b1[j] = *(const short8*)&Bs[1][(wn + j * 16 + lr) * 32 + lk * 8];
    }
#pragma unroll
    for (int i = 0; i < 4; ++i)
#pragma unroll
      for (int j = 0; j < 4; ++j) {
        acc0[i][j] = __builtin_amdgcn_mfma_f32_16x16x32_bf16(a[i], b0[j], acc0[i][j], 0, 0, 0);
        if constexpr (NUMB == 2)
          acc1[i][j] = __builtin_amdgcn_mfma_f32_16x16x32_bf16(a[i], b1[j], acc1[i][j], 0, 0, 0);
      }
    __syncthreads();   // LDS reuse next iteration
  }

  // epilogue: C/D layout col=lane&15, row=(lane>>4)*4+r  [m89-verified]
#pragma unroll
  for (int i = 0; i < 4; ++i) {
#pragma unroll
    for (int j = 0; j < 4; ++j) {
      const int col = n0 + wn + j * 16 + lr;
#pragma unroll
      for (int r = 0; r < 4; ++r) {
        const int m = wm + i * 16 + lk * 4 + r;
        if constexpr (MODE == 0) {
          if (m0 + m < mlim) {
            const int hrow = rowE[m];
            obf[(size_t)hrow * LDC + col] = f2bf(silu_f(acc0[i][j][r]));
          }
        } else if constexpr (MODE == 1) {
          if (m0 + m < mlim) {
            const int t = rowE[m] >> 1;
            atomicAdd(&ofp[(size_t)t * LDC + col], rowW[m] * acc0[i][j][r]);
          }
        } else if constexpr (MODE == 2) {
          const float v = silu_f(acc0[i][j][r]) * acc1[i][j][r];
          obf[(size_t)(m0 + m) * LDC + col] = f2bf(v);
        } else {
          ofp[(size_t)(m0 + m) * LDC + col] += acc0[i][j][r];
        }
      }
    }
  }
}

extern "C" void kernel_launch(void* const* d_in, const int* in_sizes, int n_in,
                              void* d_out, int out_size, void* d_ws, size_t ws_size,
                              hipStream_t stream) {
  const float* x    = (const float*)d_in[0];
  const float* gw   = (const float*)d_in[1];
  const float* w1   = (const float*)d_in[2];
  const float* w2   = (const float*)d_in[3];
  const float* sgg  = (const float*)d_in[4];
  const float* sgu  = (const float*)d_in[5];
  const float* sgd  = (const float*)d_in[6];
  float* out = (float*)d_out;

  char* ws = (char*)d_ws;
  size_t off = 0;
  auto take = [&](size_t bytes) {
    size_t r = off; off += (bytes + 255) & ~(size_t)255; return r;
  };
  int*    counts = (int*)   (ws + take(NEXP * sizeof(int)));
  int*    elist  = (int*)   (ws + take((size_t)NEXP * CAP * sizeof(int)));
  float*  wlist  = (float*) (ws + take((size_t)NEXP * CAP * sizeof(float)));
  int*    tIdx   = (int*)   (ws + take((size_t)NTOK * sizeof(int)));
  float2* tW     = (float2*)(ws + take((size_t)NTOK * sizeof(float2)));
  u16*    Xb     = (u16*)   (ws + take((size_t)NTOK * DDIM * 2));
  u16*    W1b    = (u16*)   (ws + take((size_t)NEXP * HDIM * DDIM * 2));
  u16*    W2b    = (u16*)   (ws + take((size_t)NEXP * DDIM * HDIM * 2));
  u16*    SGGb   = (u16*)   (ws + take((size_t)HDIM * DDIM * 2));
  u16*    SGUb   = (u16*)   (ws + take((size_t)HDIM * DDIM * 2));
  u16*    SGDb   = (u16*)   (ws + take((size_t)DDIM * HDIM * 2));
  u16*    Hbuf   = (u16*)   (ws + take((size_t)NTOK * 2 * HDIM * 2));
  u16*    ACT    = (u16*)   (ws + take((size_t)NTOK * HDIM * 2));
  if (off > ws_size) return;  // fail loudly (out stays zero)

  hipMemsetAsync(out, 0, (size_t)out_size * sizeof(float), stream);

  cvt_all<<<dim3(512, 6), 256, 0, stream>>>(x, w1, w2, sgg, sgu, sgd,
                                            Xb, W1b, W2b, SGGb, SGUb, SGDb);
  router_topk<<<NTOK / 4, 256, 0, stream>>>(x, gw, tIdx, tW);
  build_lists<<<NEXP, 256, 0, stream>>>(tIdx, tW, counts, elist, wlist);

  // routed up: M<=n_e, N=1024, K=512
  gemm_tn<0, DDIM, HDIM><<<dim3(HDIM / 128, 32, NEXP), 256, 0, stream>>>(
      Xb, W1b, nullptr, Hbuf, nullptr, counts, elist, wlist);
  // routed down: M<=n_e, N=512, K=1024, atomic weighted add into out
  gemm_tn<1, HDIM, DDIM><<<dim3(DDIM / 128, 32, NEXP), 256, 0, stream>>>(
      Hbuf, W2b, nullptr, nullptr, out, counts, elist, wlist);
  // shared gate/up: M=4096, N=1024, K=512
  gemm_tn<2, DDIM, HDIM><<<dim3(HDIM / 128, NTOK / 128, 1), 256, 0, stream>>>(
      Xb, SGGb, SGUb, ACT, nullptr, nullptr, nullptr, nullptr);
  // shared down: M=4096, N=512, K=1024, out += (runs after routed atomics)
  gemm_tn<3, HDIM, DDIM><<<dim3(DDIM / 128, NTOK / 128, 1), 256, 0, stream>>>(
      ACT, SGDb, nullptr, nullptr, out, nullptr, nullptr, nullptr);
}

// Round 3
// 141.264 us; speedup vs baseline: 1.6355x; 1.0471x over previous
//
#include <hip/hip_runtime.h>
#include <hip/hip_bf16.h>

// MoE: B=2,S=2048,D=512,E=8,H=1024,TOP_K=2. fp32 in/out, bf16 MFMA internally.
// Pipeline: cvt(fp32->bf16) -> router_topk -> build_lists
//           -> GEMM0 (routed up, silu->Hbuf) -> GEMM1 (routed down -> eo, plain stores)
//           -> GEMM2 (shared gate/up, silu*up -> ACT) -> GEMM3 (shared down, WRITES out)
//           -> combine (out += w0*eo[2t] + w1*eo[2t+1]).
// No memset of out: GEMM3 fully overwrites it each call (replay-safe).
// eo aliases W1b (dead after GEMM0).

#define NTOK 4096
#define DDIM 512
#define HDIM 1024
#define NEXP 8
#define CAP  4096

typedef unsigned short u16;
typedef __attribute__((ext_vector_type(8))) short short8;
typedef __attribute__((ext_vector_type(4))) float f32x4;

__device__ __forceinline__ u16 f2bf(float f) {
  unsigned u = __float_as_uint(f);
  u += 0x7fffu + ((u >> 16) & 1u);   // RNE
  return (u16)(u >> 16);
}
__device__ __forceinline__ float bf2f(u16 v) {
  return __uint_as_float(((unsigned)v) << 16);
}

__device__ __forceinline__ float silu_f(float v) { return v / (1.0f + __expf(-v)); }

__device__ __forceinline__ void gload16(const u16* g, u16* l) {
  __builtin_amdgcn_global_load_lds((const __attribute__((address_space(1))) void*)g,
                                   (__attribute__((address_space(3))) void*)l, 16, 0, 0);
}

// ---------------- fp32 -> bf16 conversion for all MFMA operands ----------------
__global__ __launch_bounds__(256) void cvt_all(
    const float* __restrict__ x,  const float* __restrict__ w1,
    const float* __restrict__ w2, const float* __restrict__ sgg,
    const float* __restrict__ sgu, const float* __restrict__ sgd,
    u16* __restrict__ xb, u16* __restrict__ w1b, u16* __restrict__ w2b,
    u16* __restrict__ sggb, u16* __restrict__ sgub, u16* __restrict__ sgdb) {
  const float* src; u16* dst; int n4;
  switch (blockIdx.y) {
    case 0:  src = x;   dst = xb;   n4 = NTOK * DDIM / 4;        break;
    case 1:  src = w1;  dst = w1b;  n4 = NEXP * HDIM * DDIM / 4; break;
    case 2:  src = w2;  dst = w2b;  n4 = NEXP * HDIM * DDIM / 4; break;
    case 3:  src = sgg; dst = sggb; n4 = HDIM * DDIM / 4;        break;
    case 4:  src = sgu; dst = sgub; n4 = HDIM * DDIM / 4;        break;
    default: src = sgd; dst = sgdb; n4 = HDIM * DDIM / 4;        break;
  }
  int i = blockIdx.x * blockDim.x + threadIdx.x;
  const int stride = gridDim.x * blockDim.x;
  for (; i < n4; i += stride) {
    float4 v = ((const float4*)src)[i];
    ushort4 o;
    o.x = f2bf(v.x); o.y = f2bf(v.y); o.z = f2bf(v.z); o.w = f2bf(v.w);
    ((ushort4*)dst)[i] = o;
  }
}

// ---------------- router phase 1: fp32 logits, top-2, softmax (no atomics) ------
__global__ __launch_bounds__(256) void router_topk(
    const float* __restrict__ x, const float* __restrict__ gw,
    int* __restrict__ tIdx, float2* __restrict__ tW) {
  const int lane = threadIdx.x & 63;
  const int wid  = threadIdx.x >> 6;
  const int t = blockIdx.x * 4 + wid;           // one wave per token
  const float4* xr = (const float4*)(x + (size_t)t * DDIM + lane * 8);
  const float4 x0 = xr[0], x1 = xr[1];
  float p[NEXP];
#pragma unroll
  for (int e = 0; e < NEXP; ++e) {
    const float4* gr = (const float4*)(gw + (size_t)e * DDIM + lane * 8);
    const float4 g0 = gr[0], g1 = gr[1];
    p[e] = x0.x*g0.x + x0.y*g0.y + x0.z*g0.z + x0.w*g0.w +
           x1.x*g1.x + x1.y*g1.y + x1.z*g1.z + x1.w*g1.w;
  }
#pragma unroll
  for (int e = 0; e < NEXP; ++e) {
#pragma unroll
    for (int m = 32; m >= 1; m >>= 1) p[e] += __shfl_xor(p[e], m);
  }
  if (lane == 0) {
    int i0 = 0; float v0 = p[0];
#pragma unroll
    for (int e = 1; e < NEXP; ++e) if (p[e] > v0) { v0 = p[e]; i0 = e; }
    int i1 = -1; float v1 = -3.0e38f;
#pragma unroll
    for (int e = 0; e < NEXP; ++e) if (e != i0 && p[e] > v1) { v1 = p[e]; i1 = e; }
    const float ex1 = __expf(v1 - v0);          // v0 >= v1
    const float inv = 1.0f / (1.0f + ex1);
    tIdx[t] = i0 | (i1 << 4);
    tW[t] = make_float2(inv, ex1 * inv);
  }
}

// ---------------- router phase 2: per-expert list build (ballot + LDS counter) --
__global__ __launch_bounds__(256) void build_lists(
    const int* __restrict__ tIdx,
    int* __restrict__ counts, int* __restrict__ elist) {
  const int e = blockIdx.x;
  __shared__ int cnt;
  if (threadIdx.x == 0) cnt = 0;
  __syncthreads();
  const int lane = threadIdx.x & 63;
  int* el = elist + e * CAP;
  for (int base = 0; base < NTOK; base += 256) {
    const int t = base + threadIdx.x;
    const int pk = tIdx[t];
#pragma unroll
    for (int slot = 0; slot < 2; ++slot) {
      const bool m = (((pk >> (slot * 4)) & 15) == e);
      const unsigned long long b = __ballot(m);
      const int my  = __popcll(b & ((1ull << lane) - 1));
      const int tot = __popcll(b);
      int wbase = 0;
      if (lane == 0 && tot) wbase = atomicAdd(&cnt, tot);
      wbase = __shfl(wbase, 0);
      if (m) el[wbase + my] = t * 2 + slot;
    }
  }
  __syncthreads();
  if (threadIdx.x == 0) counts[e] = cnt;
}

// ---------------- TN GEMM template, 128x128 tile, BK=32, 4 waves ----------------
// MODE 0: routed up   — gather Xb rows (entry>>1), silu -> Hbuf[entry]
// MODE 1: routed down — gather Hbuf rows (entry), plain store -> eo[entry] (bf16)
// MODE 2: shared g/up — A=Xb, two B; silu(c0)*c1 -> ACT
// MODE 3: shared down — A=ACT; out = acc (plain store, full coverage)
template <int MODE, int KDIM, int NFULL>
__global__ __launch_bounds__(256) void gemm_tn(
    const u16* __restrict__ A, const u16* __restrict__ B0, const u16* __restrict__ B1,
    u16* __restrict__ obf, float* __restrict__ ofp,
    const int* __restrict__ counts, const int* __restrict__ elist) {
  constexpr int NUMB  = (MODE == 2) ? 2 : 1;
  constexpr int KSTEP = KDIM / 32;
  constexpr int LDC   = (MODE == 0 || MODE == 2) ? HDIM : DDIM;
  const int n0 = blockIdx.x * 128;
  const int m0 = blockIdx.y * 128;

  int mlim;
  const u16* Bp0 = B0;
  const int* lst = nullptr;
  if constexpr (MODE == 0 || MODE == 1) {
    const int e = blockIdx.z;
    mlim = counts[e];
    lst = elist + e * CAP;
    Bp0 = B0 + (size_t)e * NFULL * KDIM;
  } else {
    mlim = NTOK;
  }
  if (m0 >= mlim) return;

  __shared__ __align__(16) u16 As[128 * 32];
  __shared__ __align__(16) u16 Bs[NUMB][128 * 32];
  __shared__ int rowE[128];

  const int tid  = threadIdx.x;
  const int wid  = tid >> 6, lane = tid & 63;

  if constexpr (MODE == 0 || MODE == 1) {
    if (tid < 128) {
      int idx = m0 + tid; if (idx > mlim - 1) idx = mlim - 1;  // clamp padding rows
      rowE[tid] = lst[idx];
    }
    __syncthreads();
  }

  // staging: 2 x 16B per thread per operand per K-step; LDS dest linear per wave
  const u16* aG[2]; const u16* bG0[2]; const u16* bG1[2];
  u16* aL[2]; u16* bL0[2]; u16* bL1[2];
#pragma unroll
  for (int p = 0; p < 2; ++p) {
    const int slot = (wid + p * 4) * 64 + lane;   // 0..511
    const int r = slot >> 2, kc = slot & 3;
    aL[p]  = As + slot * 8;
    bL0[p] = &Bs[0][slot * 8];
    int arow;
    if constexpr (MODE == 0)      arow = rowE[r] >> 1;
    else if constexpr (MODE == 1) arow = rowE[r];
    else                          arow = m0 + r;
    aG[p]  = A   + (size_t)arow * KDIM + kc * 8;
    bG0[p] = Bp0 + (size_t)(n0 + r) * KDIM + kc * 8;
    if constexpr (NUMB == 2) {
      bL1[p] = &Bs[1][slot * 8];
      bG1[p] = B1 + (size_t)(n0 + r) * KDIM + kc * 8;
    }
  }

  const int wm = (wid >> 1) * 64, wn = (wid & 1) * 64;
  const int lr = lane & 15, lk = lane >> 4;

  const f32x4 zero = {0.f, 0.f, 0.f, 0.f};
  f32x4 acc0[4][4], acc1[4][4];
#pragma unroll
  for (int i = 0; i < 4; ++i)
#pragma unroll
    for (int j = 0; j < 4; ++j) { acc0[i][j] = zero; acc1[i][j] = zero; }

  for (int kt = 0; kt < KSTEP; ++kt) {
#pragma unroll
    for (int p = 0; p < 2; ++p) {
      gload16(aG[p]  + kt * 32, aL[p]);
      gload16(bG0[p] + kt * 32, bL0[p]);
      if constexpr (NUMB == 2) gload16(bG1[p] + kt * 32, bL1[p]);
    }
    __syncthreads();   // drains vmcnt (incl. global_load_lds) before reads

    short8 a[4], b0[4], b1[4];
#pragma unroll
    for (int i = 0; i < 4; ++i)
      a[i] = *(const short8*)&As[(wm + i * 16 + lr) * 32 + lk * 8];
#pragma unroll
    for (int j = 0; j < 4; ++j)
      b0[j] = *(const short8*)&Bs[0][(wn + j * 16 + lr) * 32 + lk * 8];
    if constexpr (NUMB == 2) {
#pragma unroll
      for (int j = 0; j < 4; ++j)
        b1[j] = *(const short8*)&Bs[1][(wn + j * 16 + lr) * 32 + lk * 8];
    }
#pragma unroll
    for (int i = 0; i < 4; ++i)
#pragma unroll
      for (int j = 0; j < 4; ++j) {
        acc0[i][j] = __builtin_amdgcn_mfma_f32_16x16x32_bf16(a[i], b0[j], acc0[i][j], 0, 0, 0);
        if constexpr (NUMB == 2)
          acc1[i][j] = __builtin_amdgcn_mfma_f32_16x16x32_bf16(a[i], b1[j], acc1[i][j], 0, 0, 0);
      }
    __syncthreads();   // LDS reuse next iteration
  }

  // epilogue: C/D layout col=lane&15, row=(lane>>4)*4+r  [m89-verified]
#pragma unroll
  for (int i = 0; i < 4; ++i) {
#pragma unroll
    for (int j = 0; j < 4; ++j) {
      const int col = n0 + wn + j * 16 + lr;
#pragma unroll
      for (int r = 0; r < 4; ++r) {
        const int m = wm + i * 16 + lk * 4 + r;
        if constexpr (MODE == 0) {
          if (m0 + m < mlim) {
            const int hrow = rowE[m];
            obf[(size_t)hrow * LDC + col] = f2bf(silu_f(acc0[i][j][r]));
          }
        } else if constexpr (MODE == 1) {
          if (m0 + m < mlim) {
            obf[(size_t)rowE[m] * LDC + col] = f2bf(acc0[i][j][r]);
          }
        } else if constexpr (MODE == 2) {
          const float v = silu_f(acc0[i][j][r]) * acc1[i][j][r];
          obf[(size_t)(m0 + m) * LDC + col] = f2bf(v);
        } else {
          ofp[(size_t)(m0 + m) * LDC + col] = acc0[i][j][r];
        }
      }
    }
  }
}

// ---------------- final combine: out[t] += w0*eo[2t] + w1*eo[2t+1] --------------
__global__ __launch_bounds__(256) void combine_kernel(
    const u16* __restrict__ eo, const float2* __restrict__ tW,
    float* __restrict__ out) {
  const int g = blockIdx.x * 256 + threadIdx.x;   // one thread per 8 cols
  const int t = g >> 6;                            // 512/8 = 64 chunks per token
  const int c0 = (g & 63) * 8;
  const float2 w = tW[t];
  const short8 e0 = *(const short8*)&eo[(size_t)(t * 2) * DDIM + c0];
  const short8 e1 = *(const short8*)&eo[(size_t)(t * 2 + 1) * DDIM + c0];
  float* o = out + (size_t)t * DDIM + c0;
  float4 o0 = ((float4*)o)[0], o1 = ((float4*)o)[1];
  o0.x += w.x * bf2f((u16)e0[0]) + w.y * bf2f((u16)e1[0]);
  o0.y += w.x * bf2f((u16)e0[1]) + w.y * bf2f((u16)e1[1]);
  o0.z += w.x * bf2f((u16)e0[2]) + w.y * bf2f((u16)e1[2]);
  o0.w += w.x * bf2f((u16)e0[3]) + w.y * bf2f((u16)e1[3]);
  o1.x += w.x * bf2f((u16)e0[4]) + w.y * bf2f((u16)e1[4]);
  o1.y += w.x * bf2f((u16)e0[5]) + w.y * bf2f((u16)e1[5]);
  o1.z += w.x * bf2f((u16)e0[6]) + w.y * bf2f((u16)e1[6]);
  o1.w += w.x * bf2f((u16)e0[7]) + w.y * bf2f((u16)e1[7]);
  ((float4*)o)[0] = o0; ((float4*)o)[1] = o1;
}

extern "C" void kernel_launch(void* const* d_in, const int* in_sizes, int n_in,
                              void* d_out, int out_size, void* d_ws, size_t ws_size,
                              hipStream_t stream) {
  const float* x    = (const float*)d_in[0];
  const float* gw   = (const float*)d_in[1];
  const float* w1   = (const float*)d_in[2];
  const float* w2   = (const float*)d_in[3];
  const float* sgg  = (const float*)d_in[4];
  const float* sgu  = (const float*)d_in[5];
  const float* sgd  = (const float*)d_in[6];
  float* out = (float*)d_out;

  char* ws = (char*)d_ws;
  size_t off = 0;
  auto take = [&](size_t bytes) {
    size_t r = off; off += (bytes + 255) & ~(size_t)255; return r;
  };
  int*    counts = (int*)   (ws + take(NEXP * sizeof(int)));
  int*    elist  = (int*)   (ws + take((size_t)NEXP * CAP * sizeof(int)));
  int*    tIdx   = (int*)   (ws + take((size_t)NTOK * sizeof(int)));
  float2* tW     = (float2*)(ws + take((size_t)NTOK * sizeof(float2)));
  u16*    Xb     = (u16*)   (ws + take((size_t)NTOK * DDIM * 2));
  u16*    W1b    = (u16*)   (ws + take((size_t)NEXP * HDIM * DDIM * 2));
  u16*    W2b    = (u16*)   (ws + take((size_t)NEXP * DDIM * HDIM * 2));
  u16*    SGGb   = (u16*)   (ws + take((size_t)HDIM * DDIM * 2));
  u16*    SGUb   = (u16*)   (ws + take((size_t)HDIM * DDIM * 2));
  u16*    SGDb   = (u16*)   (ws + take((size_t)DDIM * HDIM * 2));
  u16*    Hbuf   = (u16*)   (ws + take((size_t)NTOK * 2 * HDIM * 2));
  u16*    ACT    = (u16*)   (ws + take((size_t)NTOK * HDIM * 2));
  u16*    eo     = W1b;     // alias: W1b dead after GEMM0; eo = 8192x512 bf16 = 8MB
  if (off > ws_size) return;  // fail loudly (out stays zero)

  cvt_all<<<dim3(512, 6), 256, 0, stream>>>(x, w1, w2, sgg, sgu, sgd,
                                            Xb, W1b, W2b, SGGb, SGUb, SGDb);
  router_topk<<<NTOK / 4, 256, 0, stream>>>(x, gw, tIdx, tW);
  build_lists<<<NEXP, 256, 0, stream>>>(tIdx, counts, elist);

  // routed up: M<=n_e, N=1024, K=512, silu -> Hbuf
  gemm_tn<0, DDIM, HDIM><<<dim3(HDIM / 128, 32, NEXP), 256, 0, stream>>>(
      Xb, W1b, nullptr, Hbuf, nullptr, counts, elist);
  // routed down: M<=n_e, N=512, K=1024, plain bf16 store -> eo (aliases W1b)
  gemm_tn<1, HDIM, DDIM><<<dim3(DDIM / 128, 32, NEXP), 256, 0, stream>>>(
      Hbuf, W2b, nullptr, eo, nullptr, counts, elist);
  // shared gate/up: M=4096, N=1024, K=512, silu*up -> ACT
  gemm_tn<2, DDIM, HDIM><<<dim3(HDIM / 128, NTOK / 128, 1), 256, 0, stream>>>(
      Xb, SGGb, SGUb, ACT, nullptr, nullptr, nullptr);
  // shared down: M=4096, N=512, K=1024, WRITES out (no memset needed)
  gemm_tn<3, HDIM, DDIM><<<dim3(DDIM / 128, NTOK / 128, 1), 256, 0, stream>>>(
      ACT, SGDb, nullptr, nullptr, out, nullptr, nullptr);
  // out += w0*eo[2t] + w1*eo[2t+1]
  combine_kernel<<<NTOK * 64 / 256, 256, 0, stream>>>(eo, tW, out);
}

// Round 4
// 137.445 us; speedup vs baseline: 1.6810x; 1.0278x over previous
//
#include <hip/hip_runtime.h>
#include <hip/hip_bf16.h>

// MoE: B=2,S=2048,D=512,E=8,H=1024,TOP_K=2. fp32 in/out, bf16 MFMA internally.
// 5 launches: prep (cvt weights + router + Xb cvt) -> build_lists
//   -> gemm_up   (z<8: routed up silu->Hbuf | z==8: shared gate/up silu*up->ACT)
//   -> gemm_down (z<8: routed down ->eo     | z==8: shared down WRITES out)
//   -> combine   (out += w0*eo[2t] + w1*eo[2t+1]).
// GEMMs: 128x128 tile, BK=32, 4 waves, 2-phase double-buffered LDS pipeline
// (prefetch next K-tile via global_load_lds before ds_read of current; ONE
// __syncthreads per K-step — its vmcnt(0) drain is the pipeline boundary).
// eo aliases W1b (dead after gemm_up, fully rewritten by prep each call).

#define NTOK 4096
#define DDIM 512
#define HDIM 1024
#define NEXP 8
#define CAP  4096

typedef unsigned short u16;
typedef __attribute__((ext_vector_type(8))) short short8;
typedef __attribute__((ext_vector_type(4))) float f32x4;

__device__ __forceinline__ u16 f2bf(float f) {
  unsigned u = __float_as_uint(f);
  u += 0x7fffu + ((u >> 16) & 1u);   // RNE
  return (u16)(u >> 16);
}
__device__ __forceinline__ float bf2f(u16 v) {
  return __uint_as_float(((unsigned)v) << 16);
}
__device__ __forceinline__ float silu_f(float v) { return v / (1.0f + __expf(-v)); }

__device__ __forceinline__ void gload16(const u16* g, u16* l) {
  __builtin_amdgcn_global_load_lds((const __attribute__((address_space(1))) void*)g,
                                   (__attribute__((address_space(3))) void*)l, 16, 0, 0);
}

// ---------------- prep: router (blocks 0..1023) + all weight cvt (rest) --------
__global__ __launch_bounds__(256) void prep(
    const float* __restrict__ x,   const float* __restrict__ gw,
    const float* __restrict__ w1,  const float* __restrict__ w2,
    const float* __restrict__ sgg, const float* __restrict__ sgu,
    const float* __restrict__ sgd,
    u16* __restrict__ Xb, u16* __restrict__ W1b, u16* __restrict__ W2b,
    u16* __restrict__ SGGb, u16* __restrict__ SGUb, u16* __restrict__ SGDb,
    int* __restrict__ tIdx, float2* __restrict__ tW) {
  if (blockIdx.x < NTOK / 4) {
    // --- router + x conversion: one wave per token ---
    const int lane = threadIdx.x & 63;
    const int wid  = threadIdx.x >> 6;
    const int t = blockIdx.x * 4 + wid;
    const float4* xr = (const float4*)(x + (size_t)t * DDIM + lane * 8);
    const float4 x0 = xr[0], x1 = xr[1];
    short8 xbv;
    xbv[0]=f2bf(x0.x); xbv[1]=f2bf(x0.y); xbv[2]=f2bf(x0.z); xbv[3]=f2bf(x0.w);
    xbv[4]=f2bf(x1.x); xbv[5]=f2bf(x1.y); xbv[6]=f2bf(x1.z); xbv[7]=f2bf(x1.w);
    *(short8*)&Xb[(size_t)t * DDIM + lane * 8] = xbv;
    float p[NEXP];
#pragma unroll
    for (int e = 0; e < NEXP; ++e) {
      const float4* gr = (const float4*)(gw + (size_t)e * DDIM + lane * 8);
      const float4 g0 = gr[0], g1 = gr[1];
      p[e] = x0.x*g0.x + x0.y*g0.y + x0.z*g0.z + x0.w*g0.w +
             x1.x*g1.x + x1.y*g1.y + x1.z*g1.z + x1.w*g1.w;
    }
#pragma unroll
    for (int e = 0; e < NEXP; ++e) {
#pragma unroll
      for (int m = 32; m >= 1; m >>= 1) p[e] += __shfl_xor(p[e], m);
    }
    if (lane == 0) {
      int i0 = 0; float v0 = p[0];
#pragma unroll
      for (int e = 1; e < NEXP; ++e) if (p[e] > v0) { v0 = p[e]; i0 = e; }
      int i1 = -1; float v1 = -3.0e38f;
#pragma unroll
      for (int e = 0; e < NEXP; ++e) if (e != i0 && p[e] > v1) { v1 = p[e]; i1 = e; }
      const float ex1 = __expf(v1 - v0);        // v0 >= v1
      const float inv = 1.0f / (1.0f + ex1);
      tIdx[t] = i0 | (i1 << 4);
      tW[t] = make_float2(inv, ex1 * inv);
    }
  } else {
    // --- weight fp32 -> bf16, grid-stride over concatenated [w1|w2|sgg|sgu|sgd]
    constexpr int NW1 = NEXP * HDIM * DDIM / 4;   // float4 count
    constexpr int NSG = HDIM * DDIM / 4;
    constexpr int TOT = 2 * NW1 + 3 * NSG;
    int i = (blockIdx.x - NTOK / 4) * 256 + threadIdx.x;
    const int stride = (gridDim.x - NTOK / 4) * 256;
    for (; i < TOT; i += stride) {
      const float* s; u16* d; int j = i;
      if (j < NW1)               { s = w1;  d = W1b;  }
      else if ((j -= NW1) < NW1) { s = w2;  d = W2b;  }
      else if ((j -= NW1) < NSG) { s = sgg; d = SGGb; }
      else if ((j -= NSG) < NSG) { s = sgu; d = SGUb; }
      else        { j -= NSG;      s = sgd; d = SGDb; }
      float4 v = ((const float4*)s)[j];
      ushort4 o;
      o.x = f2bf(v.x); o.y = f2bf(v.y); o.z = f2bf(v.z); o.w = f2bf(v.w);
      ((ushort4*)d)[j] = o;
    }
  }
}

// ---------------- per-expert list build (ballot + LDS counter) ------------------
__global__ __launch_bounds__(256) void build_lists(
    const int* __restrict__ tIdx,
    int* __restrict__ counts, int* __restrict__ elist) {
  const int e = blockIdx.x;
  __shared__ int cnt;
  if (threadIdx.x == 0) cnt = 0;
  __syncthreads();
  const int lane = threadIdx.x & 63;
  int* el = elist + e * CAP;
  for (int base = 0; base < NTOK; base += 256) {
    const int t = base + threadIdx.x;
    const int pk = tIdx[t];
#pragma unroll
    for (int slot = 0; slot < 2; ++slot) {
      const bool m = (((pk >> (slot * 4)) & 15) == e);
      const unsigned long long b = __ballot(m);
      const int my  = __popcll(b & ((1ull << lane) - 1));
      const int tot = __popcll(b);
      int wbase = 0;
      if (lane == 0 && tot) wbase = atomicAdd(&cnt, tot);
      wbase = __shfl(wbase, 0);
      if (m) el[wbase + my] = t * 2 + slot;
    }
  }
  __syncthreads();
  if (threadIdx.x == 0) counts[e] = cnt;
}

// ---------------- up GEMM: K=512. z<8 routed (silu->Hbuf), z==8 shared g/up ----
__global__ __launch_bounds__(256) void gemm_up(
    const u16* __restrict__ Xb, const u16* __restrict__ W1b,
    const u16* __restrict__ SGGb, const u16* __restrict__ SGUb,
    u16* __restrict__ Hbuf, u16* __restrict__ ACT,
    const int* __restrict__ counts, const int* __restrict__ elist) {
  constexpr int KDIM = DDIM, KSTEP = KDIM / 32;
  const bool sh = (blockIdx.z == NEXP);
  const int n0 = blockIdx.x * 128;
  const int m0 = blockIdx.y * 128;

  int mlim; const u16* Bp0; const u16* Bp1 = nullptr; const int* lst = nullptr;
  if (!sh) {
    const int e = blockIdx.z;
    mlim = counts[e];
    lst = elist + e * CAP;
    Bp0 = W1b + (size_t)e * HDIM * KDIM;
  } else {
    mlim = NTOK;
    Bp0 = SGGb; Bp1 = SGUb;
  }
  if (m0 >= mlim) return;

  __shared__ __align__(16) u16 As[2][128 * 32];
  __shared__ __align__(16) u16 Bs0[2][128 * 32];
  __shared__ __align__(16) u16 Bs1[2][128 * 32];
  __shared__ int rowE[128];

  const int tid = threadIdx.x;
  const int wid = tid >> 6, lane = tid & 63;

  if (!sh) {
    if (tid < 128) {
      int idx = m0 + tid; if (idx > mlim - 1) idx = mlim - 1;
      rowE[tid] = lst[idx];
    }
    __syncthreads();
  }

  const u16 *aG[2], *bG0[2], *bG1[2];
  u16 *aL[2][2], *bL0[2][2], *bL1[2][2];
#pragma unroll
  for (int p = 0; p < 2; ++p) {
    const int slot = (wid + p * 4) * 64 + lane;   // 0..511
    const int r = slot >> 2, kc = slot & 3;
#pragma unroll
    for (int c = 0; c < 2; ++c) {
      aL[c][p]  = &As[c][slot * 8];
      bL0[c][p] = &Bs0[c][slot * 8];
      bL1[c][p] = &Bs1[c][slot * 8];
    }
    const int arow = sh ? (m0 + r) : (rowE[r] >> 1);
    aG[p]  = Xb  + (size_t)arow * KDIM + kc * 8;
    bG0[p] = Bp0 + (size_t)(n0 + r) * KDIM + kc * 8;
    if (sh) bG1[p] = Bp1 + (size_t)(n0 + r) * KDIM + kc * 8;
  }

  const int wm = (wid >> 1) * 64, wn = (wid & 1) * 64;
  const int lr = lane & 15, lk = lane >> 4;

  const f32x4 zero = {0.f, 0.f, 0.f, 0.f};
  f32x4 acc0[4][4], acc1[4][4];
#pragma unroll
  for (int i = 0; i < 4; ++i)
#pragma unroll
    for (int j = 0; j < 4; ++j) { acc0[i][j] = zero; acc1[i][j] = zero; }

  auto STAGE = [&](int kt, int c) {
#pragma unroll
    for (int p = 0; p < 2; ++p) {
      gload16(aG[p]  + kt * 32, aL[c][p]);
      gload16(bG0[p] + kt * 32, bL0[c][p]);
      if (sh) gload16(bG1[p] + kt * 32, bL1[c][p]);
    }
  };

  STAGE(0, 0);
  __syncthreads();                       // vmcnt(0) drain: buf0 ready
  int cur = 0;
  for (int kt = 0; kt < KSTEP; ++kt) {
    if (kt + 1 < KSTEP) STAGE(kt + 1, cur ^ 1);  // prefetch in flight over compute
    short8 a[4], b0[4], b1[4];
#pragma unroll
    for (int i = 0; i < 4; ++i)
      a[i] = *(const short8*)&As[cur][(wm + i * 16 + lr) * 32 + lk * 8];
#pragma unroll
    for (int j = 0; j < 4; ++j)
      b0[j] = *(const short8*)&Bs0[cur][(wn + j * 16 + lr) * 32 + lk * 8];
    if (sh) {
#pragma unroll
      for (int j = 0; j < 4; ++j)
        b1[j] = *(const short8*)&Bs1[cur][(wn + j * 16 + lr) * 32 + lk * 8];
    }
#pragma unroll
    for (int i = 0; i < 4; ++i)
#pragma unroll
      for (int j = 0; j < 4; ++j) {
        acc0[i][j] = __builtin_amdgcn_mfma_f32_16x16x32_bf16(a[i], b0[j], acc0[i][j], 0, 0, 0);
        if (sh)
          acc1[i][j] = __builtin_amdgcn_mfma_f32_16x16x32_bf16(a[i], b1[j], acc1[i][j], 0, 0, 0);
      }
    __syncthreads();                     // drains vmcnt(0): next buf ready; reuse safe
    cur ^= 1;
  }

  // epilogue: C/D layout col=lane&15, row=(lane>>4)*4+r  [m89-verified]
#pragma unroll
  for (int i = 0; i < 4; ++i) {
#pragma unroll
    for (int j = 0; j < 4; ++j) {
      const int col = n0 + wn + j * 16 + lr;
#pragma unroll
      for (int r = 0; r < 4; ++r) {
        const int m = wm + i * 16 + lk * 4 + r;
        if (!sh) {
          if (m0 + m < mlim)
            Hbuf[(size_t)rowE[m] * HDIM + col] = f2bf(silu_f(acc0[i][j][r]));
        } else {
          ACT[(size_t)(m0 + m) * HDIM + col] =
              f2bf(silu_f(acc0[i][j][r]) * acc1[i][j][r]);
        }
      }
    }
  }
}

// ---------------- down GEMM: K=1024. z<8 routed (->eo), z==8 shared (->out) ----
__global__ __launch_bounds__(256) void gemm_down(
    const u16* __restrict__ Hbuf, const u16* __restrict__ W2b,
    const u16* __restrict__ ACT,  const u16* __restrict__ SGDb,
    u16* __restrict__ eo, float* __restrict__ out,
    const int* __restrict__ counts, const int* __restrict__ elist) {
  constexpr int KDIM = HDIM, KSTEP = KDIM / 32;
  const bool sh = (blockIdx.z == NEXP);
  const int n0 = blockIdx.x * 128;
  const int m0 = blockIdx.y * 128;

  int mlim; const u16* Ap; const u16* Bp0; const int* lst = nullptr;
  if (!sh) {
    const int e = blockIdx.z;
    mlim = counts[e];
    lst = elist + e * CAP;
    Ap = Hbuf;
    Bp0 = W2b + (size_t)e * DDIM * KDIM;
  } else {
    mlim = NTOK;
    Ap = ACT;
    Bp0 = SGDb;
  }
  if (m0 >= mlim) return;

  __shared__ __align__(16) u16 As[2][128 * 32];
  __shared__ __align__(16) u16 Bs0[2][128 * 32];
  __shared__ int rowE[128];

  const int tid = threadIdx.x;
  const int wid = tid >> 6, lane = tid & 63;

  if (!sh) {
    if (tid < 128) {
      int idx = m0 + tid; if (idx > mlim - 1) idx = mlim - 1;
      rowE[tid] = lst[idx];
    }
    __syncthreads();
  }

  const u16 *aG[2], *bG0[2];
  u16 *aL[2][2], *bL0[2][2];
#pragma unroll
  for (int p = 0; p < 2; ++p) {
    const int slot = (wid + p * 4) * 64 + lane;
    const int r = slot >> 2, kc = slot & 3;
#pragma unroll
    for (int c = 0; c < 2; ++c) {
      aL[c][p]  = &As[c][slot * 8];
      bL0[c][p] = &Bs0[c][slot * 8];
    }
    const int arow = sh ? (m0 + r) : rowE[r];
    aG[p]  = Ap  + (size_t)arow * KDIM + kc * 8;
    bG0[p] = Bp0 + (size_t)(n0 + r) * KDIM + kc * 8;
  }

  const int wm = (wid >> 1) * 64, wn = (wid & 1) * 64;
  const int lr = lane & 15, lk = lane >> 4;

  const f32x4 zero = {0.f, 0.f, 0.f, 0.f};
  f32x4 acc0[4][4];
#pragma unroll
  for (int i = 0; i < 4; ++i)
#pragma unroll
    for (int j = 0; j < 4; ++j) acc0[i][j] = zero;

  auto STAGE = [&](int kt, int c) {
#pragma unroll
    for (int p = 0; p < 2; ++p) {
      gload16(aG[p]  + kt * 32, aL[c][p]);
      gload16(bG0[p] + kt * 32, bL0[c][p]);
    }
  };

  STAGE(0, 0);
  __syncthreads();
  int cur = 0;
  for (int kt = 0; kt < KSTEP; ++kt) {
    if (kt + 1 < KSTEP) STAGE(kt + 1, cur ^ 1);
    short8 a[4], b0[4];
#pragma unroll
    for (int i = 0; i < 4; ++i)
      a[i] = *(const short8*)&As[cur][(wm + i * 16 + lr) * 32 + lk * 8];
#pragma unroll
    for (int j = 0; j < 4; ++j)
      b0[j] = *(const short8*)&Bs0[cur][(wn + j * 16 + lr) * 32 + lk * 8];
#pragma unroll
    for (int i = 0; i < 4; ++i)
#pragma unroll
      for (int j = 0; j < 4; ++j)
        acc0[i][j] = __builtin_amdgcn_mfma_f32_16x16x32_bf16(a[i], b0[j], acc0[i][j], 0, 0, 0);
    __syncthreads();
    cur ^= 1;
  }

#pragma unroll
  for (int i = 0; i < 4; ++i) {
#pragma unroll
    for (int j = 0; j < 4; ++j) {
      const int col = n0 + wn + j * 16 + lr;
#pragma unroll
      for (int r = 0; r < 4; ++r) {
        const int m = wm + i * 16 + lk * 4 + r;
        if (!sh) {
          if (m0 + m < mlim)
            eo[(size_t)rowE[m] * DDIM + col] = f2bf(acc0[i][j][r]);
        } else {
          out[(size_t)(m0 + m) * DDIM + col] = acc0[i][j][r];   // full overwrite
        }
      }
    }
  }
}

// ---------------- final combine: out[t] += w0*eo[2t] + w1*eo[2t+1] --------------
__global__ __launch_bounds__(256) void combine_kernel(
    const u16* __restrict__ eo, const float2* __restrict__ tW,
    float* __restrict__ out) {
  const int g = blockIdx.x * 256 + threadIdx.x;   // one thread per 8 cols
  const int t = g >> 6;
  const int c0 = (g & 63) * 8;
  const float2 w = tW[t];
  const short8 e0 = *(const short8*)&eo[(size_t)(t * 2) * DDIM + c0];
  const short8 e1 = *(const short8*)&eo[(size_t)(t * 2 + 1) * DDIM + c0];
  float* o = out + (size_t)t * DDIM + c0;
  float4 o0 = ((float4*)o)[0], o1 = ((float4*)o)[1];
  o0.x += w.x * bf2f((u16)e0[0]) + w.y * bf2f((u16)e1[0]);
  o0.y += w.x * bf2f((u16)e0[1]) + w.y * bf2f((u16)e1[1]);
  o0.z += w.x * bf2f((u16)e0[2]) + w.y * bf2f((u16)e1[2]);
  o0.w += w.x * bf2f((u16)e0[3]) + w.y * bf2f((u16)e1[3]);
  o1.x += w.x * bf2f((u16)e0[4]) + w.y * bf2f((u16)e1[4]);
  o1.y += w.x * bf2f((u16)e0[5]) + w.y * bf2f((u16)e1[5]);
  o1.z += w.x * bf2f((u16)e0[6]) + w.y * bf2f((u16)e1[6]);
  o1.w += w.x * bf2f((u16)e0[7]) + w.y * bf2f((u16)e1[7]);
  ((float4*)o)[0] = o0; ((float4*)o)[1] = o1;
}

extern "C" void kernel_launch(void* const* d_in, const int* in_sizes, int n_in,
                              void* d_out, int out_size, void* d_ws, size_t ws_size,
                              hipStream_t stream) {
  const float* x    = (const float*)d_in[0];
  const float* gw   = (const float*)d_in[1];
  const float* w1   = (const float*)d_in[2];
  const float* w2   = (const float*)d_in[3];
  const float* sgg  = (const float*)d_in[4];
  const float* sgu  = (const float*)d_in[5];
  const float* sgd  = (const float*)d_in[6];
  float* out = (float*)d_out;

  char* ws = (char*)d_ws;
  size_t off = 0;
  auto take = [&](size_t bytes) {
    size_t r = off; off += (bytes + 255) & ~(size_t)255; return r;
  };
  int*    counts = (int*)   (ws + take(NEXP * sizeof(int)));
  int*    elist  = (int*)   (ws + take((size_t)NEXP * CAP * sizeof(int)));
  int*    tIdx   = (int*)   (ws + take((size_t)NTOK * sizeof(int)));
  float2* tW     = (float2*)(ws + take((size_t)NTOK * sizeof(float2)));
  u16*    Xb     = (u16*)   (ws + take((size_t)NTOK * DDIM * 2));
  u16*    W1b    = (u16*)   (ws + take((size_t)NEXP * HDIM * DDIM * 2));
  u16*    W2b    = (u16*)   (ws + take((size_t)NEXP * DDIM * HDIM * 2));
  u16*    SGGb   = (u16*)   (ws + take((size_t)HDIM * DDIM * 2));
  u16*    SGUb   = (u16*)   (ws + take((size_t)HDIM * DDIM * 2));
  u16*    SGDb   = (u16*)   (ws + take((size_t)DDIM * HDIM * 2));
  u16*    Hbuf   = (u16*)   (ws + take((size_t)NTOK * 2 * HDIM * 2));
  u16*    ACT    = (u16*)   (ws + take((size_t)NTOK * HDIM * 2));
  u16*    eo     = W1b;     // alias: W1b dead after gemm_up; rewritten by prep
  if (off > ws_size) return;

  prep<<<dim3(3072), 256, 0, stream>>>(x, gw, w1, w2, sgg, sgu, sgd,
                                       Xb, W1b, W2b, SGGb, SGUb, SGDb, tIdx, tW);
  build_lists<<<NEXP, 256, 0, stream>>>(tIdx, counts, elist);
  gemm_up<<<dim3(HDIM / 128, 32, NEXP + 1), 256, 0, stream>>>(
      Xb, W1b, SGGb, SGUb, Hbuf, ACT, counts, elist);
  gemm_down<<<dim3(DDIM / 128, 32, NEXP + 1), 256, 0, stream>>>(
      Hbuf, W2b, ACT, SGDb, eo, out, counts, elist);
  combine_kernel<<<NTOK * 64 / 256, 256, 0, stream>>>(eo, tW, out);
}

// Round 5
// 125.136 us; speedup vs baseline: 1.8463x; 1.0984x over previous
//
#include <hip/hip_runtime.h>
#include <hip/hip_bf16.h>

// MoE: B=2,S=2048,D=512,E=8,H=1024,TOP_K=2. fp32 in/out, bf16 MFMA internally.
// 6 launches: prep (weights cvt + router + Xb cvt) -> build_lists
//   -> gemm_up   (z<8 routed silu->Hbuf | z=8 gate silu->Gtmp | z=9 up->Utmp)
//   -> fuse_act  (ACT = Gtmp * Utmp)
//   -> gemm_down (z<8 routed ->eo | z=8 shared down WRITES out)
//   -> combine   (out += w0*eo[2t] + w1*eo[2t+1]).
// GEMM core: 128x128 tile, BK=32, 4 waves, uniform 2-operand blocks,
// 2-deep counted-vmcnt pipeline (T4): prologue stages tiles 0,1; per K-step
//   s_waitcnt vmcnt(4); s_barrier;          // tile kt landed, kt+1 in flight
//   ds_read frags; lgkmcnt(0); sched_barrier(0); s_barrier;  // LDS slot free
//   STAGE(kt+2) into freed buffer; MFMA.
// NO __syncthreads in the loop (it would drain vmcnt(0) and expose latency).
// eo aliases W1b (dead after gemm_up, rewritten by prep each call).

#define NTOK 4096
#define DDIM 512
#define HDIM 1024
#define NEXP 8
#define CAP  4096

typedef unsigned short u16;
typedef __attribute__((ext_vector_type(8))) short short8;
typedef __attribute__((ext_vector_type(4))) float f32x4;

__device__ __forceinline__ u16 f2bf(float f) {
  unsigned u = __float_as_uint(f);
  u += 0x7fffu + ((u >> 16) & 1u);   // RNE
  return (u16)(u >> 16);
}
__device__ __forceinline__ float bf2f(u16 v) {
  return __uint_as_float(((unsigned)v) << 16);
}
__device__ __forceinline__ float silu_f(float v) { return v / (1.0f + __expf(-v)); }

__device__ __forceinline__ void gload16(const u16* g, u16* l) {
  __builtin_amdgcn_global_load_lds((const __attribute__((address_space(1))) void*)g,
                                   (__attribute__((address_space(3))) void*)l, 16, 0, 0);
}

// ---------------- prep: router (blocks 0..1023) + all weight cvt (rest) --------
__global__ __launch_bounds__(256) void prep(
    const float* __restrict__ x,   const float* __restrict__ gw,
    const float* __restrict__ w1,  const float* __restrict__ w2,
    const float* __restrict__ sgg, const float* __restrict__ sgu,
    const float* __restrict__ sgd,
    u16* __restrict__ Xb, u16* __restrict__ W1b, u16* __restrict__ W2b,
    u16* __restrict__ SGGb, u16* __restrict__ SGUb, u16* __restrict__ SGDb,
    int* __restrict__ tIdx, float2* __restrict__ tW) {
  if (blockIdx.x < NTOK / 4) {
    // --- router + x conversion: one wave per token ---
    const int lane = threadIdx.x & 63;
    const int wid  = threadIdx.x >> 6;
    const int t = blockIdx.x * 4 + wid;
    const float4* xr = (const float4*)(x + (size_t)t * DDIM + lane * 8);
    const float4 x0 = xr[0], x1 = xr[1];
    short8 xbv;
    xbv[0]=f2bf(x0.x); xbv[1]=f2bf(x0.y); xbv[2]=f2bf(x0.z); xbv[3]=f2bf(x0.w);
    xbv[4]=f2bf(x1.x); xbv[5]=f2bf(x1.y); xbv[6]=f2bf(x1.z); xbv[7]=f2bf(x1.w);
    *(short8*)&Xb[(size_t)t * DDIM + lane * 8] = xbv;
    float p[NEXP];
#pragma unroll
    for (int e = 0; e < NEXP; ++e) {
      const float4* gr = (const float4*)(gw + (size_t)e * DDIM + lane * 8);
      const float4 g0 = gr[0], g1 = gr[1];
      p[e] = x0.x*g0.x + x0.y*g0.y + x0.z*g0.z + x0.w*g0.w +
             x1.x*g1.x + x1.y*g1.y + x1.z*g1.z + x1.w*g1.w;
    }
#pragma unroll
    for (int e = 0; e < NEXP; ++e) {
#pragma unroll
      for (int m = 32; m >= 1; m >>= 1) p[e] += __shfl_xor(p[e], m);
    }
    if (lane == 0) {
      int i0 = 0; float v0 = p[0];
#pragma unroll
      for (int e = 1; e < NEXP; ++e) if (p[e] > v0) { v0 = p[e]; i0 = e; }
      int i1 = -1; float v1 = -3.0e38f;
#pragma unroll
      for (int e = 0; e < NEXP; ++e) if (e != i0 && p[e] > v1) { v1 = p[e]; i1 = e; }
      const float ex1 = __expf(v1 - v0);        // v0 >= v1
      const float inv = 1.0f / (1.0f + ex1);
      tIdx[t] = i0 | (i1 << 4);
      tW[t] = make_float2(inv, ex1 * inv);
    }
  } else {
    // --- weight fp32 -> bf16, grid-stride over concatenated [w1|w2|sgg|sgu|sgd]
    constexpr int NW1 = NEXP * HDIM * DDIM / 4;   // float4 count
    constexpr int NSG = HDIM * DDIM / 4;
    constexpr int TOT = 2 * NW1 + 3 * NSG;
    int i = (blockIdx.x - NTOK / 4) * 256 + threadIdx.x;
    const int stride = (gridDim.x - NTOK / 4) * 256;
    for (; i < TOT; i += stride) {
      const float* s; u16* d; int j = i;
      if (j < NW1)               { s = w1;  d = W1b;  }
      else if ((j -= NW1) < NW1) { s = w2;  d = W2b;  }
      else if ((j -= NW1) < NSG) { s = sgg; d = SGGb; }
      else if ((j -= NSG) < NSG) { s = sgu; d = SGUb; }
      else        { j -= NSG;      s = sgd; d = SGDb; }
      float4 v = ((const float4*)s)[j];
      ushort4 o;
      o.x = f2bf(v.x); o.y = f2bf(v.y); o.z = f2bf(v.z); o.w = f2bf(v.w);
      ((ushort4*)d)[j] = o;
    }
  }
}

// ---------------- per-expert list build (ballot + LDS counter) ------------------
__global__ __launch_bounds__(256) void build_lists(
    const int* __restrict__ tIdx,
    int* __restrict__ counts, int* __restrict__ elist) {
  const int e = blockIdx.x;
  __shared__ int cnt;
  if (threadIdx.x == 0) cnt = 0;
  __syncthreads();
  const int lane = threadIdx.x & 63;
  int* el = elist + e * CAP;
  for (int base = 0; base < NTOK; base += 256) {
    const int t = base + threadIdx.x;
    const int pk = tIdx[t];
#pragma unroll
    for (int slot = 0; slot < 2; ++slot) {
      const bool m = (((pk >> (slot * 4)) & 15) == e);
      const unsigned long long b = __ballot(m);
      const int my  = __popcll(b & ((1ull << lane) - 1));
      const int tot = __popcll(b);
      int wbase = 0;
      if (lane == 0 && tot) wbase = atomicAdd(&cnt, tot);
      wbase = __shfl(wbase, 0);
      if (m) el[wbase + my] = t * 2 + slot;
    }
  }
  __syncthreads();
  if (threadIdx.x == 0) counts[e] = cnt;
}

// ---------------- up GEMM: K=512, N=1024 ---------------------------------------
// z<8: routed expert z (A = Xb gathered, silu -> Hbuf[entry])
// z=8: shared gate (A = Xb, silu -> Gtmp) ; z=9: shared up (A = Xb, -> Utmp)
__global__ __launch_bounds__(256, 4) void gemm_up(
    const u16* __restrict__ Xb, const u16* __restrict__ W1b,
    const u16* __restrict__ SGGb, const u16* __restrict__ SGUb,
    u16* __restrict__ Hbuf, u16* __restrict__ Gtmp, u16* __restrict__ Utmp,
    const int* __restrict__ counts, const int* __restrict__ elist) {
  constexpr int KDIM = DDIM, KSTEP = KDIM / 32;
  const int z = blockIdx.z;
  const int n0 = blockIdx.x * 128;
  const int m0 = blockIdx.y * 128;
  const bool routed = (z < NEXP);

  int mlim; const u16* Bp; const int* lst = nullptr;
  if (routed) {
    mlim = counts[z];
    lst = elist + z * CAP;
    Bp = W1b + (size_t)z * HDIM * KDIM;
  } else {
    mlim = NTOK;
    Bp = (z == NEXP) ? SGGb : SGUb;
  }
  if (m0 >= mlim) return;

  __shared__ __align__(16) u16 As[2][128 * 32];
  __shared__ __align__(16) u16 Bs[2][128 * 32];
  __shared__ int rowE[128];

  const int tid = threadIdx.x;
  const int wid = tid >> 6, lane = tid & 63;

  if (routed) {
    if (tid < 128) {
      int idx = m0 + tid; if (idx > mlim - 1) idx = mlim - 1;
      rowE[tid] = lst[idx];
    }
    __syncthreads();
  }

  const u16 *aG[2], *bG[2];
  u16 *aL[2][2], *bL[2][2];
#pragma unroll
  for (int p = 0; p < 2; ++p) {
    const int slot = (wid + p * 4) * 64 + lane;   // 0..511
    const int r = slot >> 2, kc = slot & 3;
#pragma unroll
    for (int c = 0; c < 2; ++c) {
      aL[c][p] = &As[c][slot * 8];
      bL[c][p] = &Bs[c][slot * 8];
    }
    const int arow = routed ? (rowE[r] >> 1) : (m0 + r);
    aG[p] = Xb + (size_t)arow * KDIM + kc * 8;
    bG[p] = Bp + (size_t)(n0 + r) * KDIM + kc * 8;
  }

  const int wm = (wid >> 1) * 64, wn = (wid & 1) * 64;
  const int lr = lane & 15, lk = lane >> 4;

  const f32x4 zero = {0.f, 0.f, 0.f, 0.f};
  f32x4 acc[4][4];
#pragma unroll
  for (int i = 0; i < 4; ++i)
#pragma unroll
    for (int j = 0; j < 4; ++j) acc[i][j] = zero;

  auto STAGE = [&](int kt, int c) {
#pragma unroll
    for (int p = 0; p < 2; ++p) {
      gload16(aG[p] + kt * 32, aL[c][p]);
      gload16(bG[p] + kt * 32, bL[c][p]);
    }
  };

  STAGE(0, 0);          // 4 loads/wave in flight
  STAGE(1, 1);          // 8
  int cur = 0;
  for (int kt = 0; kt < KSTEP; ++kt) {
    if (kt + 1 < KSTEP) asm volatile("s_waitcnt vmcnt(4)" ::: "memory");
    else                asm volatile("s_waitcnt vmcnt(0)" ::: "memory");
    __builtin_amdgcn_s_barrier();            // tile kt fully in LDS (all waves)
    short8 a[4], b[4];
#pragma unroll
    for (int i = 0; i < 4; ++i)
      a[i] = *(const short8*)&As[cur][(wm + i * 16 + lr) * 32 + lk * 8];
#pragma unroll
    for (int j = 0; j < 4; ++j)
      b[j] = *(const short8*)&Bs[cur][(wn + j * 16 + lr) * 32 + lk * 8];
    asm volatile("s_waitcnt lgkmcnt(0)" ::: "memory");
    __builtin_amdgcn_sched_barrier(0);       // rule #18: pin reads before barrier
    __builtin_amdgcn_s_barrier();            // all waves done reading buf[cur]
    if (kt + 2 < KSTEP) STAGE(kt + 2, cur);  // overwrite freed buffer
#pragma unroll
    for (int i = 0; i < 4; ++i)
#pragma unroll
      for (int j = 0; j < 4; ++j)
        acc[i][j] = __builtin_amdgcn_mfma_f32_16x16x32_bf16(a[i], b[j], acc[i][j], 0, 0, 0);
    cur ^= 1;
  }

  // epilogue: C/D layout col=lane&15, row=(lane>>4)*4+r  [m89-verified]
#pragma unroll
  for (int i = 0; i < 4; ++i) {
#pragma unroll
    for (int j = 0; j < 4; ++j) {
      const int col = n0 + wn + j * 16 + lr;
#pragma unroll
      for (int r = 0; r < 4; ++r) {
        const int m = wm + i * 16 + lk * 4 + r;
        if (routed) {
          if (m0 + m < mlim)
            Hbuf[(size_t)rowE[m] * HDIM + col] = f2bf(silu_f(acc[i][j][r]));
        } else if (z == NEXP) {
          Gtmp[(size_t)(m0 + m) * HDIM + col] = f2bf(silu_f(acc[i][j][r]));
        } else {
          Utmp[(size_t)(m0 + m) * HDIM + col] = f2bf(acc[i][j][r]);
        }
      }
    }
  }
}

// ---------------- ACT = Gtmp(silu'd) * Utmp ------------------------------------
__global__ __launch_bounds__(256) void fuse_act(
    const u16* __restrict__ G, const u16* __restrict__ U, u16* __restrict__ ACT) {
  const int i = blockIdx.x * 256 + threadIdx.x;   // one thread per 8 elems
  const short8 g = *(const short8*)&G[(size_t)i * 8];
  const short8 u = *(const short8*)&U[(size_t)i * 8];
  short8 o;
#pragma unroll
  for (int k = 0; k < 8; ++k)
    o[k] = (short)f2bf(bf2f((u16)g[k]) * bf2f((u16)u[k]));
  *(short8*)&ACT[(size_t)i * 8] = o;
}

// ---------------- down GEMM: K=1024, N=512 -------------------------------------
// z<8: routed (A = Hbuf gathered, -> eo[entry] bf16)
// z=8: shared down (A = ACT, -> out fp32, full overwrite)
__global__ __launch_bounds__(256, 4) void gemm_down(
    const u16* __restrict__ Hbuf, const u16* __restrict__ W2b,
    const u16* __restrict__ ACT,  const u16* __restrict__ SGDb,
    u16* __restrict__ eo, float* __restrict__ out,
    const int* __restrict__ counts, const int* __restrict__ elist) {
  constexpr int KDIM = HDIM, KSTEP = KDIM / 32;
  const int z = blockIdx.z;
  const int n0 = blockIdx.x * 128;
  const int m0 = blockIdx.y * 128;
  const bool routed = (z < NEXP);

  int mlim; const u16* Ap; const u16* Bp; const int* lst = nullptr;
  if (routed) {
    mlim = counts[z];
    lst = elist + z * CAP;
    Ap = Hbuf;
    Bp = W2b + (size_t)z * DDIM * KDIM;
  } else {
    mlim = NTOK;
    Ap = ACT;
    Bp = SGDb;
  }
  if (m0 >= mlim) return;

  __shared__ __align__(16) u16 As[2][128 * 32];
  __shared__ __align__(16) u16 Bs[2][128 * 32];
  __shared__ int rowE[128];

  const int tid = threadIdx.x;
  const int wid = tid >> 6, lane = tid & 63;

  if (routed) {
    if (tid < 128) {
      int idx = m0 + tid; if (idx > mlim - 1) idx = mlim - 1;
      rowE[tid] = lst[idx];
    }
    __syncthreads();
  }

  const u16 *aG[2], *bG[2];
  u16 *aL[2][2], *bL[2][2];
#pragma unroll
  for (int p = 0; p < 2; ++p) {
    const int slot = (wid + p * 4) * 64 + lane;
    const int r = slot >> 2, kc = slot & 3;
#pragma unroll
    for (int c = 0; c < 2; ++c) {
      aL[c][p] = &As[c][slot * 8];
      bL[c][p] = &Bs[c][slot * 8];
    }
    const int arow = routed ? rowE[r] : (m0 + r);
    aG[p] = Ap + (size_t)arow * KDIM + kc * 8;
    bG[p] = Bp + (size_t)(n0 + r) * KDIM + kc * 8;
  }

  const int wm = (wid >> 1) * 64, wn = (wid & 1) * 64;
  const int lr = lane & 15, lk = lane >> 4;

  const f32x4 zero = {0.f, 0.f, 0.f, 0.f};
  f32x4 acc[4][4];
#pragma unroll
  for (int i = 0; i < 4; ++i)
#pragma unroll
    for (int j = 0; j < 4; ++j) acc[i][j] = zero;

  auto STAGE = [&](int kt, int c) {
#pragma unroll
    for (int p = 0; p < 2; ++p) {
      gload16(aG[p] + kt * 32, aL[c][p]);
      gload16(bG[p] + kt * 32, bL[c][p]);
    }
  };

  STAGE(0, 0);
  STAGE(1, 1);
  int cur = 0;
  for (int kt = 0; kt < KSTEP; ++kt) {
    if (kt + 1 < KSTEP) asm volatile("s_waitcnt vmcnt(4)" ::: "memory");
    else                asm volatile("s_waitcnt vmcnt(0)" ::: "memory");
    __builtin_amdgcn_s_barrier();
    short8 a[4], b[4];
#pragma unroll
    for (int i = 0; i < 4; ++i)
      a[i] = *(const short8*)&As[cur][(wm + i * 16 + lr) * 32 + lk * 8];
#pragma unroll
    for (int j = 0; j < 4; ++j)
      b[j] = *(const short8*)&Bs[cur][(wn + j * 16 + lr) * 32 + lk * 8];
    asm volatile("s_waitcnt lgkmcnt(0)" ::: "memory");
    __builtin_amdgcn_sched_barrier(0);
    __builtin_amdgcn_s_barrier();
    if (kt + 2 < KSTEP) STAGE(kt + 2, cur);
#pragma unroll
    for (int i = 0; i < 4; ++i)
#pragma unroll
      for (int j = 0; j < 4; ++j)
        acc[i][j] = __builtin_amdgcn_mfma_f32_16x16x32_bf16(a[i], b[j], acc[i][j], 0, 0, 0);
    cur ^= 1;
  }

#pragma unroll
  for (int i = 0; i < 4; ++i) {
#pragma unroll
    for (int j = 0; j < 4; ++j) {
      const int col = n0 + wn + j * 16 + lr;
#pragma unroll
      for (int r = 0; r < 4; ++r) {
        const int m = wm + i * 16 + lk * 4 + r;
        if (routed) {
          if (m0 + m < mlim)
            eo[(size_t)rowE[m] * DDIM + col] = f2bf(acc[i][j][r]);
        } else {
          out[(size_t)(m0 + m) * DDIM + col] = acc[i][j][r];   // full overwrite
        }
      }
    }
  }
}

// ---------------- final combine: out[t] += w0*eo[2t] + w1*eo[2t+1] --------------
__global__ __launch_bounds__(256) void combine_kernel(
    const u16* __restrict__ eo, const float2* __restrict__ tW,
    float* __restrict__ out) {
  const int g = blockIdx.x * 256 + threadIdx.x;   // one thread per 8 cols
  const int t = g >> 6;
  const int c0 = (g & 63) * 8;
  const float2 w = tW[t];
  const short8 e0 = *(const short8*)&eo[(size_t)(t * 2) * DDIM + c0];
  const short8 e1 = *(const short8*)&eo[(size_t)(t * 2 + 1) * DDIM + c0];
  float* o = out + (size_t)t * DDIM + c0;
  float4 o0 = ((float4*)o)[0], o1 = ((float4*)o)[1];
  o0.x += w.x * bf2f((u16)e0[0]) + w.y * bf2f((u16)e1[0]);
  o0.y += w.x * bf2f((u16)e0[1]) + w.y * bf2f((u16)e1[1]);
  o0.z += w.x * bf2f((u16)e0[2]) + w.y * bf2f((u16)e1[2]);
  o0.w += w.x * bf2f((u16)e0[3]) + w.y * bf2f((u16)e1[3]);
  o1.x += w.x * bf2f((u16)e0[4]) + w.y * bf2f((u16)e1[4]);
  o1.y += w.x * bf2f((u16)e0[5]) + w.y * bf2f((u16)e1[5]);
  o1.z += w.x * bf2f((u16)e0[6]) + w.y * bf2f((u16)e1[6]);
  o1.w += w.x * bf2f((u16)e0[7]) + w.y * bf2f((u16)e1[7]);
  ((float4*)o)[0] = o0; ((float4*)o)[1] = o1;
}

extern "C" void kernel_launch(void* const* d_in, const int* in_sizes, int n_in,
                              void* d_out, int out_size, void* d_ws, size_t ws_size,
                              hipStream_t stream) {
  const float* x    = (const float*)d_in[0];
  const float* gw   = (const float*)d_in[1];
  const float* w1   = (const float*)d_in[2];
  const float* w2   = (const float*)d_in[3];
  const float* sgg  = (const float*)d_in[4];
  const float* sgu  = (const float*)d_in[5];
  const float* sgd  = (const float*)d_in[6];
  float* out = (float*)d_out;

  char* ws = (char*)d_ws;
  size_t off = 0;
  auto take = [&](size_t bytes) {
    size_t r = off; off += (bytes + 255) & ~(size_t)255; return r;
  };
  int*    counts = (int*)   (ws + take(NEXP * sizeof(int)));
  int*    elist  = (int*)   (ws + take((size_t)NEXP * CAP * sizeof(int)));
  int*    tIdx   = (int*)   (ws + take((size_t)NTOK * sizeof(int)));
  float2* tW     = (float2*)(ws + take((size_t)NTOK * sizeof(float2)));
  u16*    Xb     = (u16*)   (ws + take((size_t)NTOK * DDIM * 2));
  u16*    W1b    = (u16*)   (ws + take((size_t)NEXP * HDIM * DDIM * 2));
  u16*    W2b    = (u16*)   (ws + take((size_t)NEXP * DDIM * HDIM * 2));
  u16*    SGGb   = (u16*)   (ws + take((size_t)HDIM * DDIM * 2));
  u16*    SGUb   = (u16*)   (ws + take((size_t)HDIM * DDIM * 2));
  u16*    SGDb   = (u16*)   (ws + take((size_t)DDIM * HDIM * 2));
  u16*    Hbuf   = (u16*)   (ws + take((size_t)NTOK * 2 * HDIM * 2));
  u16*    ACT    = (u16*)   (ws + take((size_t)NTOK * HDIM * 2));
  u16*    Gtmp   = (u16*)   (ws + take((size_t)NTOK * HDIM * 2));
  u16*    Utmp   = (u16*)   (ws + take((size_t)NTOK * HDIM * 2));
  u16*    eo     = W1b;     // alias: W1b dead after gemm_up; rewritten by prep
  if (off > ws_size) return;

  prep<<<dim3(3072), 256, 0, stream>>>(x, gw, w1, w2, sgg, sgu, sgd,
                                       Xb, W1b, W2b, SGGb, SGUb, SGDb, tIdx, tW);
  build_lists<<<NEXP, 256, 0, stream>>>(tIdx, counts, elist);
  gemm_up<<<dim3(HDIM / 128, 32, NEXP + 2), 256, 0, stream>>>(
      Xb, W1b, SGGb, SGUb, Hbuf, Gtmp, Utmp, counts, elist);
  fuse_act<<<NTOK * HDIM / 8 / 256, 256, 0, stream>>>(Gtmp, Utmp, ACT);
  gemm_down<<<dim3(DDIM / 128, 32, NEXP + 1), 256, 0, stream>>>(
      Hbuf, W2b, ACT, SGDb, eo, out, counts, elist);
  combine_kernel<<<NTOK * 64 / 256, 256, 0, stream>>>(eo, tW, out);
}